// Round 6
// baseline (339.839 us; speedup 1.0000x reference)
//
#include <hip/hip_runtime.h>
#include <hip/hip_bf16.h>

#define NB 2
#define NS 2048
#define NH 16
#define ND 128
#define HID2 2048
#define MROWS 4096   // NB*NS

typedef __bf16 bf16;
typedef bf16 bf16x8 __attribute__((ext_vector_type(8)));
typedef bf16 bf16x4 __attribute__((ext_vector_type(4)));
typedef float f32x4 __attribute__((ext_vector_type(4)));
typedef unsigned int u32;

#define GLOBAL_AS __attribute__((address_space(1)))
#define LDS_AS __attribute__((address_space(3)))

__device__ __forceinline__ void async16(void* lds, const void* g) {
    __builtin_amdgcn_global_load_lds((const GLOBAL_AS u32*)g, (LDS_AS u32*)lds, 16, 0, 0);
}

// ---------------------------------------------------------------- converts
__global__ void cvt_f32_bf16(const float* __restrict__ src, bf16* __restrict__ dst, int n8) {
    int i = blockIdx.x * blockDim.x + threadIdx.x;
    if (i >= n8) return;
    const float4* s4 = (const float4*)src;
    float4 a = s4[2 * i], b = s4[2 * i + 1];
    bf16x8 o;
    o[0] = (bf16)a.x; o[1] = (bf16)a.y; o[2] = (bf16)a.z; o[3] = (bf16)a.w;
    o[4] = (bf16)b.x; o[5] = (bf16)b.y; o[6] = (bf16)b.z; o[7] = (bf16)b.w;
    ((bf16x8*)dst)[i] = o;
}

__global__ void cvt_w4(const float* __restrict__ Wq, const float* __restrict__ Wk,
                       const float* __restrict__ Wv, const float* __restrict__ Wo,
                       bf16* __restrict__ dst) {
    int z = blockIdx.y;
    const float* src = (z == 0) ? Wq : (z == 1) ? Wk : (z == 2) ? Wv : Wo;
    int i = blockIdx.x * blockDim.x + threadIdx.x;
    const float4* s4 = (const float4*)src;
    float4 a = s4[2 * i], b = s4[2 * i + 1];
    bf16x8 o;
    o[0] = (bf16)a.x; o[1] = (bf16)a.y; o[2] = (bf16)a.z; o[3] = (bf16)a.w;
    o[4] = (bf16)b.x; o[5] = (bf16)b.y; o[6] = (bf16)b.z; o[7] = (bf16)b.w;
    ((bf16x8*)(dst + (size_t)z * HID2 * HID2))[i] = o;
}

__global__ void qscale_kernel(const float* qr, const float* qi, const float* qm,
                              const float* kr, const float* ki, const float* km,
                              const float* vr, const float* vi, const float* vm,
                              float* out) {
    int i = blockIdx.x * blockDim.x + threadIdx.x;
    if (i >= HID2) return;
    out[i]            = sqrtf(qr[i] * qr[i] + qi[i] * qi[i]) * fabsf(qm[i]);
    out[HID2 + i]     = sqrtf(kr[i] * kr[i] + ki[i] * ki[i]) * fabsf(km[i]);
    out[2 * HID2 + i] = sqrtf(vr[i] * vr[i] + vi[i] * vi[i]) * fabsf(vm[i]);
}

// ---------------------------------------------------------------- 256x256 8-phase GEMM
// C[M,N] = A[M,K] @ Bt[N,K]^T. Tile 256x256, BK=64, 8 waves (2M x 4N), 512 thr.
// Wave owns 128x64 out: acc[8][4] (0.375 ds_reads/MFMA -> MFMA-bound).
// 2 LDS K-tile slots (64KB each). Per K-tile: 4 phases (mh,kk quadrants), each
// {ds_read; (ph0: stage16 next tile); barrier; lgkmcnt(0); setprio1; 16 MFMA;
//  setprio0; barrier}. vmcnt(0) only at phase 3 (issue-to-wait ~3 phases >>
// HBM latency -> near-zero stall). Swizzle byte ^= (row&7)<<4 (proven 0-conflict).
__device__ __forceinline__ void stage16(const char* gA, const char* gB, char* sa, char* sb,
                                        int w, int lane, size_t kb) {
#pragma unroll
    for (int j = 0; j < 4; ++j) {
        int r = j * 64 + w * 8 + (lane >> 3);
        async16(sa + (j * 64 + w * 8) * 128,
                gA + (size_t)r * (HID2 * 2) + kb + (((lane & 7) * 16) ^ ((r & 7) << 4)));
    }
#pragma unroll
    for (int j = 0; j < 4; ++j) {
        int r = j * 64 + w * 8 + (lane >> 3);
        async16(sb + (j * 64 + w * 8) * 128,
                gB + (size_t)r * (HID2 * 2) + kb + (((lane & 7) * 16) ^ ((r & 7) << 4)));
    }
}

#define G_BARRIER() do { asm volatile("" ::: "memory"); __builtin_amdgcn_s_barrier(); \
                         asm volatile("" ::: "memory"); } while (0)

template <int MODE>  // 0: bf16 out = |acc+bias|*scale ; 1: f32 out = acc+bias
__device__ __forceinline__ void gemm256_core(const bf16* __restrict__ A, const bf16* __restrict__ Bt,
                                             const float* __restrict__ bias, const float* __restrict__ scale,
                                             void* __restrict__ Cout, int tm, int tn) {
    __shared__ bf16 sA[2][256 * 64];
    __shared__ bf16 sB[2][256 * 64];
    const int NT = HID2 / 64;  // 32
    int tid = threadIdx.x, w = tid >> 6, lane = tid & 63;
    int wr = w >> 2, wc = w & 3;          // wave tile: rows wr*128..+127, cols wc*64..+63
    int l15 = lane & 15, l4 = lane >> 4;
    int xorb = (l15 & 7) << 4;
    int kc0 = (l4 * 16) ^ xorb;
    int kc1 = (64 + l4 * 16) ^ xorb;
    int arow = wr * 128 + l15;
    int brow = wc * 64 + l15;

    const char* gA = (const char*)A + (size_t)tm * 256 * (HID2 * 2);
    const char* gB = (const char*)Bt + (size_t)tn * 256 * (HID2 * 2);

    f32x4 acc[8][4] = {};

    stage16(gA, gB, (char*)sA[0], (char*)sB[0], w, lane, 0);
    asm volatile("s_waitcnt vmcnt(0)" ::: "memory");
    G_BARRIER();

    int cur = 0;
    for (int t = 0; t < NT; ++t) {
        const char* pa = (const char*)sA[cur];
        const char* pb = (const char*)sB[cur];
        const bool pre = (t + 1 < NT);
        bf16x8 af[4], bg[4];

        // ---- phase 0: quadrant (mh=0, kk=0); stage tile t+1
#pragma unroll
        for (int n = 0; n < 4; ++n) bg[n] = *(const bf16x8*)(pb + (brow + n * 16) * 128 + kc0);
#pragma unroll
        for (int m = 0; m < 4; ++m) af[m] = *(const bf16x8*)(pa + (arow + m * 16) * 128 + kc0);
        if (pre) stage16(gA, gB, (char*)sA[cur ^ 1], (char*)sB[cur ^ 1], w, lane, (size_t)(t + 1) * 128);
        G_BARRIER();
        asm volatile("s_waitcnt lgkmcnt(0)" ::: "memory");
        __builtin_amdgcn_sched_barrier(0);
        __builtin_amdgcn_s_setprio(1);
#pragma unroll
        for (int m = 0; m < 4; ++m)
#pragma unroll
            for (int n = 0; n < 4; ++n)
                acc[m][n] = __builtin_amdgcn_mfma_f32_16x16x32_bf16(af[m], bg[n], acc[m][n], 0, 0, 0);
        __builtin_amdgcn_s_setprio(0);
        G_BARRIER();

        // ---- phase 1: quadrant (mh=1, kk=0)
#pragma unroll
        for (int m = 0; m < 4; ++m) af[m] = *(const bf16x8*)(pa + (arow + 64 + m * 16) * 128 + kc0);
        G_BARRIER();
        asm volatile("s_waitcnt lgkmcnt(0)" ::: "memory");
        __builtin_amdgcn_sched_barrier(0);
        __builtin_amdgcn_s_setprio(1);
#pragma unroll
        for (int m = 0; m < 4; ++m)
#pragma unroll
            for (int n = 0; n < 4; ++n)
                acc[4 + m][n] = __builtin_amdgcn_mfma_f32_16x16x32_bf16(af[m], bg[n], acc[4 + m][n], 0, 0, 0);
        __builtin_amdgcn_s_setprio(0);
        G_BARRIER();

        // ---- phase 2: quadrant (mh=0, kk=1)
#pragma unroll
        for (int n = 0; n < 4; ++n) bg[n] = *(const bf16x8*)(pb + (brow + n * 16) * 128 + kc1);
#pragma unroll
        for (int m = 0; m < 4; ++m) af[m] = *(const bf16x8*)(pa + (arow + m * 16) * 128 + kc1);
        G_BARRIER();
        asm volatile("s_waitcnt lgkmcnt(0)" ::: "memory");
        __builtin_amdgcn_sched_barrier(0);
        __builtin_amdgcn_s_setprio(1);
#pragma unroll
        for (int m = 0; m < 4; ++m)
#pragma unroll
            for (int n = 0; n < 4; ++n)
                acc[m][n] = __builtin_amdgcn_mfma_f32_16x16x32_bf16(af[m], bg[n], acc[m][n], 0, 0, 0);
        __builtin_amdgcn_s_setprio(0);
        G_BARRIER();

        // ---- phase 3: quadrant (mh=1, kk=1); drain this tile's prefetch
#pragma unroll
        for (int m = 0; m < 4; ++m) af[m] = *(const bf16x8*)(pa + (arow + 64 + m * 16) * 128 + kc1);
        G_BARRIER();
        asm volatile("s_waitcnt lgkmcnt(0)" ::: "memory");
        __builtin_amdgcn_sched_barrier(0);
        __builtin_amdgcn_s_setprio(1);
#pragma unroll
        for (int m = 0; m < 4; ++m)
#pragma unroll
            for (int n = 0; n < 4; ++n)
                acc[4 + m][n] = __builtin_amdgcn_mfma_f32_16x16x32_bf16(af[m], bg[n], acc[4 + m][n], 0, 0, 0);
        __builtin_amdgcn_s_setprio(0);
        if (pre) { asm volatile("s_waitcnt vmcnt(0)" ::: "memory"); }
        G_BARRIER();

        cur ^= 1;
    }

    // epilogue
#pragma unroll
    for (int n = 0; n < 4; ++n) {
        int col = tn * 256 + wc * 64 + n * 16 + l15;
        float bv = bias[col];
        float sc = (MODE == 0) ? scale[col] : 0.f;
#pragma unroll
        for (int m = 0; m < 8; ++m) {
            int row = tm * 256 + wr * 128 + m * 16 + l4 * 4;
            if (MODE == 0) {
                bf16* Cp = (bf16*)Cout;
#pragma unroll
                for (int r = 0; r < 4; ++r)
                    Cp[(size_t)(row + r) * HID2 + col] = (bf16)(fabsf(acc[m][n][r] + bv) * sc);
            } else {
                float* Cp = (float*)Cout;
#pragma unroll
                for (int r = 0; r < 4; ++r)
                    Cp[(size_t)(row + r) * HID2 + col] = acc[m][n][r] + bv;
            }
        }
    }
}

__global__ __launch_bounds__(512, 2) void gemm256_qkv(
    const bf16* __restrict__ X, const bf16* __restrict__ Wb,
    const float* __restrict__ bq, const float* __restrict__ bk, const float* __restrict__ bv,
    const float* __restrict__ scales, bf16* __restrict__ QKV) {
    int bid = blockIdx.x;                 // 0..383
    int tng = (bid & 7) + (bid >> 7) * 8; // global N-panel 0..23 (XCD j <- panels j, j+8, j+16)
    int tm = (bid >> 3) & 15;
    int z = tng >> 3, tn = tng & 7;
    const bf16* W = Wb + (size_t)z * HID2 * HID2;
    const float* bias = (z == 0) ? bq : (z == 1) ? bk : bv;
    gemm256_core<0>(X, W, bias, scales + z * HID2, QKV + (size_t)z * MROWS * HID2, tm, tn);
}

__global__ __launch_bounds__(512, 2) void gemm256_out(
    const bf16* __restrict__ Ctx, const bf16* __restrict__ Wo,
    const float* __restrict__ bo, float* __restrict__ out) {
    int bid = blockIdx.x;                 // 0..127
    int tn = bid & 7, tm = bid >> 3;
    gemm256_core<1>(Ctx, Wo, bo, nullptr, out, tm, tn);
}

// ---------------------------------------------------------------- V transpose
__global__ void transpose_v(const bf16* __restrict__ Vb, bf16* __restrict__ Vt) {
    int bh = blockIdx.z;
    int b = bh >> 4, h = bh & 15;
    int s0 = blockIdx.x * 64, d0 = blockIdx.y * 64;
    int tid = threadIdx.x;
    __shared__ bf16 T[64][72];
    const bf16* src = Vb + ((size_t)b * NS + s0) * HID2 + h * ND + d0;
#pragma unroll
    for (int i = 0; i < 2; ++i) {
        int r = i * 32 + (tid >> 3);
        int c = (tid & 7) * 8;
        *(bf16x8*)(&T[r][c]) = *(const bf16x8*)(src + (size_t)r * HID2 + c);
    }
    __syncthreads();
    bf16* dst = Vt + ((size_t)(b * NH + h) * ND + d0) * NS + s0;
#pragma unroll
    for (int i = 0; i < 2; ++i) {
        int dr = i * 32 + (tid >> 3);
        int sc = (tid & 7) * 8;
        bf16x8 o;
#pragma unroll
        for (int j = 0; j < 8; ++j) o[j] = T[sc + j][dr];
        *(bf16x8*)(dst + (size_t)dr * NS + sc) = o;
    }
}

// ---------------------------------------------------------------- flash attention (v2)
__device__ __forceinline__ void stage_load(const bf16* __restrict__ Kp, const bf16* __restrict__ Vp,
                                           int kt, int tid, bf16x8 kreg[4], bf16x8 vreg[4]) {
#pragma unroll
    for (int i = 0; i < 4; ++i) {
        kreg[i] = *(const bf16x8*)(Kp + (size_t)(kt * 64 + i * 16 + (tid >> 4)) * HID2 + (tid & 15) * 8);
        vreg[i] = *(const bf16x8*)(Vp + (size_t)(i * 32 + (tid >> 3)) * NS + kt * 64 + (tid & 7) * 8);
    }
}

__global__ __launch_bounds__(256, 2) void flash_kernel(
    const bf16* __restrict__ Qb, const bf16* __restrict__ Kb, const bf16* __restrict__ Vt,
    const float* __restrict__ ent, const float* __restrict__ mask, bf16* __restrict__ Ctx) {
    int qt = blockIdx.x;   // 0..15
    int bh = blockIdx.y;   // 0..31
    int b = bh >> 4, h = bh & 15;
    int tid = threadIdx.x, wid = tid >> 6, lane = tid & 63;
    int l15 = lane & 15, l4 = lane >> 4;

    __shared__ bf16 Ks[64 * 136];
    __shared__ bf16 Vs[128 * 72];
    __shared__ bf16 Ps[4][32 * 72];

    const bf16* Qp = Qb + ((size_t)b * NS + qt * 128) * HID2 + h * ND;
    const bf16* Kp = Kb + (size_t)b * NS * HID2 + h * ND;
    const bf16* Vp = Vt + (size_t)(b * NH + h) * ND * NS;
    const float* maskp = mask + (size_t)b * NS;

    bf16x8 qf[2][4];
#pragma unroll
    for (int m = 0; m < 2; ++m)
#pragma unroll
        for (int kk = 0; kk < 4; ++kk)
            qf[m][kk] = *(const bf16x8*)(Qp + (size_t)(wid * 32 + m * 16 + l15) * HID2 + kk * 32 + l4 * 8);

    float eb[4];
#pragma unroll
    for (int r = 0; r < 4; ++r) eb[r] = ent[h * NH + l4 * 4 + r];
    const float RSQD = 0.08838834764831845f;

    float mrun[2], lrun[2];
    mrun[0] = mrun[1] = -INFINITY;
    lrun[0] = lrun[1] = 0.f;
    f32x4 oacc[2][8] = {};

    bf16x8 kreg[4], vreg[4];
    stage_load(Kp, Vp, 0, tid, kreg, vreg);
#pragma unroll
    for (int i = 0; i < 4; ++i) {
        *(bf16x8*)(&Ks[(i * 16 + (tid >> 4)) * 136 + (tid & 15) * 8]) = kreg[i];
        *(bf16x8*)(&Vs[(i * 32 + (tid >> 3)) * 72 + (tid & 7) * 8]) = vreg[i];
    }

    for (int kt = 0; kt < NS / 64; ++kt) {
        __syncthreads();
        if (kt + 1 < NS / 64) stage_load(Kp, Vp, kt + 1, tid, kreg, vreg);

        f32x4 s[2][4] = {};
#pragma unroll
        for (int kk = 0; kk < 4; ++kk) {
            bf16x8 kf[4];
#pragma unroll
            for (int n = 0; n < 4; ++n)
                kf[n] = *(const bf16x8*)(&Ks[(n * 16 + l15) * 136 + kk * 32 + l4 * 8]);
#pragma unroll
            for (int m = 0; m < 2; ++m)
#pragma unroll
                for (int n = 0; n < 4; ++n)
                    s[m][n] = __builtin_amdgcn_mfma_f32_16x16x32_bf16(kf[n], qf[m][kk], s[m][n], 0, 0, 0);
        }

        float4 mk[4];
#pragma unroll
        for (int n = 0; n < 4; ++n)
            mk[n] = *(const float4*)(maskp + kt * 64 + n * 16 + l4 * 4);

#pragma unroll
        for (int mq = 0; mq < 2; ++mq) {
            float sv[4][4];
#pragma unroll
            for (int n = 0; n < 4; ++n) {
                sv[n][0] = s[mq][n][0] * RSQD + eb[0] + mk[n].x;
                sv[n][1] = s[mq][n][1] * RSQD + eb[1] + mk[n].y;
                sv[n][2] = s[mq][n][2] * RSQD + eb[2] + mk[n].z;
                sv[n][3] = s[mq][n][3] * RSQD + eb[3] + mk[n].w;
            }
            float tmax = sv[0][0];
#pragma unroll
            for (int n = 0; n < 4; ++n)
#pragma unroll
                for (int r = 0; r < 4; ++r) tmax = fmaxf(tmax, sv[n][r]);
            tmax = fmaxf(tmax, __shfl_xor(tmax, 16));
            tmax = fmaxf(tmax, __shfl_xor(tmax, 32));

            if (__any(tmax > mrun[mq] + 8.0f)) {
                float mnew = fmaxf(mrun[mq], tmax);
                float corr = __expf(mrun[mq] - mnew);
                mrun[mq] = mnew;
                lrun[mq] *= corr;
#pragma unroll
                for (int r = 0; r < 4; ++r) {
                    float cr = __shfl(corr, l4 * 4 + r);
#pragma unroll
                    for (int n = 0; n < 8; ++n) oacc[mq][n][r] *= cr;
                }
            }

            float psum = 0.f;
#pragma unroll
            for (int n = 0; n < 4; ++n) {
                bf16x4 pv;
#pragma unroll
                for (int r = 0; r < 4; ++r) {
                    float p = __expf(sv[n][r] - mrun[mq]);
                    psum += p;
                    pv[r] = (bf16)p;
                }
                *(bf16x4*)(&Ps[wid][(mq * 16 + l15) * 72 + n * 16 + l4 * 4]) = pv;
            }
            psum += __shfl_xor(psum, 16);
            psum += __shfl_xor(psum, 32);
            lrun[mq] += psum;
        }

#pragma unroll
        for (int kk = 0; kk < 2; ++kk) {
            bf16x8 pa[2], vb[8];
#pragma unroll
            for (int m = 0; m < 2; ++m)
                pa[m] = *(const bf16x8*)(&Ps[wid][(m * 16 + l15) * 72 + kk * 32 + l4 * 8]);
#pragma unroll
            for (int n = 0; n < 8; ++n)
                vb[n] = *(const bf16x8*)(&Vs[(n * 16 + l15) * 72 + kk * 32 + l4 * 8]);
#pragma unroll
            for (int m = 0; m < 2; ++m)
#pragma unroll
                for (int n = 0; n < 8; ++n)
                    oacc[m][n] = __builtin_amdgcn_mfma_f32_16x16x32_bf16(pa[m], vb[n], oacc[m][n], 0, 0, 0);
        }
        __syncthreads();
        if (kt + 1 < NS / 64) {
#pragma unroll
            for (int i = 0; i < 4; ++i) {
                *(bf16x8*)(&Ks[(i * 16 + (tid >> 4)) * 136 + (tid & 15) * 8]) = kreg[i];
                *(bf16x8*)(&Vs[(i * 32 + (tid >> 3)) * 72 + (tid & 7) * 8]) = vreg[i];
            }
        }
    }

#pragma unroll
    for (int m = 0; m < 2; ++m) {
        float inv = 1.0f / lrun[m];
        float invr[4];
#pragma unroll
        for (int r = 0; r < 4; ++r) invr[r] = __shfl(inv, l4 * 4 + r);
#pragma unroll
        for (int r = 0; r < 4; ++r) {
            int row = qt * 128 + wid * 32 + m * 16 + l4 * 4 + r;
            bf16* Cp = Ctx + ((size_t)b * NS + row) * HID2 + h * ND;
#pragma unroll
            for (int n = 0; n < 8; ++n)
                Cp[n * 16 + l15] = (bf16)(oacc[m][n][r] * invr[r]);
        }
    }
}

// ---------------------------------------------------------------- launch
extern "C" void kernel_launch(void* const* d_in, const int* in_sizes, int n_in,
                              void* d_out, int out_size, void* d_ws, size_t ws_size,
                              hipStream_t stream) {
    const float* hidden = (const float*)d_in[0];
    const float* mask   = (const float*)d_in[1];
    const float* q_real = (const float*)d_in[2];
    const float* q_imag = (const float*)d_in[3];
    const float* q_mag  = (const float*)d_in[5];
    const float* k_real = (const float*)d_in[6];
    const float* k_imag = (const float*)d_in[7];
    const float* k_mag  = (const float*)d_in[9];
    const float* v_real = (const float*)d_in[10];
    const float* v_imag = (const float*)d_in[11];
    const float* v_mag  = (const float*)d_in[13];
    const float* Wq = (const float*)d_in[14];
    const float* bq = (const float*)d_in[15];
    const float* Wk = (const float*)d_in[16];
    const float* bk = (const float*)d_in[17];
    const float* Wv = (const float*)d_in[18];
    const float* bv = (const float*)d_in[19];
    const float* Wo = (const float*)d_in[20];
    const float* bo = (const float*)d_in[21];
    const float* ent = (const float*)d_in[22];

    char* ws = (char*)d_ws;
    bf16* Xb    = (bf16*)(ws);
    bf16* Wb    = (bf16*)(ws + 16777216);        // Wq,Wk,Wv,Wo bf16 contiguous
    bf16* Wob   = (bf16*)(ws + 41943040);
    bf16* QKV   = (bf16*)(ws + 50331648);
    bf16* Vt    = (bf16*)(ws + 100663296);
    bf16* Ctx   = (bf16*)(ws + 117440512);
    float* scales = (float*)(ws + 134217728);

    cvt_f32_bf16<<<4096, 256, 0, stream>>>(hidden, Xb, MROWS * HID2 / 8);
    cvt_w4<<<dim3(2048, 4), 256, 0, stream>>>(Wq, Wk, Wv, Wo, Wb);
    qscale_kernel<<<8, 256, 0, stream>>>(q_real, q_imag, q_mag, k_real, k_imag, k_mag,
                                         v_real, v_imag, v_mag, scales);
    gemm256_qkv<<<384, 512, 0, stream>>>(Xb, Wb, bq, bk, bv, scales, QKV);
    const bf16* Vb = QKV + (size_t)2 * MROWS * HID2;
    transpose_v<<<dim3(32, 2, 32), 256, 0, stream>>>(Vb, Vt);
    flash_kernel<<<dim3(16, 32), 256, 0, stream>>>(QKV, QKV + (size_t)MROWS * HID2, Vt, ent, mask, Ctx);
    gemm256_out<<<128, 512, 0, stream>>>(Ctx, Wob, bo, (float*)d_out);
}

// Round 7
// 311.189 us; speedup vs baseline: 1.0921x; 1.0921x over previous
//
#include <hip/hip_runtime.h>
#include <hip/hip_bf16.h>

#define NB 2
#define NS 2048
#define NH 16
#define ND 128
#define HID2 2048
#define MROWS 4096   // NB*NS

typedef __bf16 bf16;
typedef bf16 bf16x8 __attribute__((ext_vector_type(8)));
typedef bf16 bf16x4 __attribute__((ext_vector_type(4)));
typedef float f32x4 __attribute__((ext_vector_type(4)));
typedef unsigned int u32;

#define GLOBAL_AS __attribute__((address_space(1)))
#define LDS_AS __attribute__((address_space(3)))

__device__ __forceinline__ void async16(void* lds, const void* g) {
    __builtin_amdgcn_global_load_lds((const GLOBAL_AS u32*)g, (LDS_AS u32*)lds, 16, 0, 0);
}

// ---------------------------------------------------------------- converts
__global__ void cvt_f32_bf16(const float* __restrict__ src, bf16* __restrict__ dst, int n8) {
    int i = blockIdx.x * blockDim.x + threadIdx.x;
    if (i >= n8) return;
    const float4* s4 = (const float4*)src;
    float4 a = s4[2 * i], b = s4[2 * i + 1];
    bf16x8 o;
    o[0] = (bf16)a.x; o[1] = (bf16)a.y; o[2] = (bf16)a.z; o[3] = (bf16)a.w;
    o[4] = (bf16)b.x; o[5] = (bf16)b.y; o[6] = (bf16)b.z; o[7] = (bf16)b.w;
    ((bf16x8*)dst)[i] = o;
}

__global__ void cvt_w4(const float* __restrict__ Wq, const float* __restrict__ Wk,
                       const float* __restrict__ Wv, const float* __restrict__ Wo,
                       bf16* __restrict__ dst) {
    int z = blockIdx.y;
    const float* src = (z == 0) ? Wq : (z == 1) ? Wk : (z == 2) ? Wv : Wo;
    int i = blockIdx.x * blockDim.x + threadIdx.x;
    const float4* s4 = (const float4*)src;
    float4 a = s4[2 * i], b = s4[2 * i + 1];
    bf16x8 o;
    o[0] = (bf16)a.x; o[1] = (bf16)a.y; o[2] = (bf16)a.z; o[3] = (bf16)a.w;
    o[4] = (bf16)b.x; o[5] = (bf16)b.y; o[6] = (bf16)b.z; o[7] = (bf16)b.w;
    ((bf16x8*)(dst + (size_t)z * HID2 * HID2))[i] = o;
}

__global__ void qscale_kernel(const float* qr, const float* qi, const float* qm,
                              const float* kr, const float* ki, const float* km,
                              const float* vr, const float* vi, const float* vm,
                              float* out) {
    int i = blockIdx.x * blockDim.x + threadIdx.x;
    if (i >= HID2) return;
    out[i]            = sqrtf(qr[i] * qr[i] + qi[i] * qi[i]) * fabsf(qm[i]);
    out[HID2 + i]     = sqrtf(kr[i] * kr[i] + ki[i] * ki[i]) * fabsf(km[i]);
    out[2 * HID2 + i] = sqrtf(vr[i] * vr[i] + vi[i] * vi[i]) * fabsf(vm[i]);
}

// ---------------------------------------------------------------- GEMM (loose sync)
// C[M,N] = A[M,K] @ Bt[N,K]^T. Block tile 128x256, BK=64, 4 waves (2M x 2N),
// per-wave 64x128 out (acc[4][8]; 0.375 ds_read_b128 per MFMA).
// Round-3 skeleton: stage-all -> syncthreads -> compute -> syncthreads (the
// compiler's vmcnt(0)-before-barrier is covered by 2 blocks/CU, proven 800TF).
// Zero-conflict swizzle (proven r5): LDS[r][c ^ ((r&7)<<4 bytes)] via
// inverse-swizzled global source; reads XOR the same pattern.
__device__ __forceinline__ void stage12(const char* gA, const char* gB,
                                        char* sa, char* sb, int w, int lane, size_t kb) {
    int r8 = lane >> 3;
    int cx = (lane & 7) * 16;
#pragma unroll
    for (int j = 0; j < 4; ++j) {
        int r = w * 32 + j * 8 + r8;
        async16(sa + (w * 32 + j * 8) * 128,
                gA + (size_t)r * (HID2 * 2) + kb + (cx ^ ((r & 7) << 4)));
    }
#pragma unroll
    for (int j = 0; j < 8; ++j) {
        int r = w * 64 + j * 8 + r8;
        async16(sb + (w * 64 + j * 8) * 128,
                gB + (size_t)r * (HID2 * 2) + kb + (cx ^ ((r & 7) << 4)));
    }
}

template <int MODE>  // 0: bf16 out = |acc+bias|*scale ; 1: f32 out = acc+bias
__device__ __forceinline__ void gemm_core(const bf16* __restrict__ A, const bf16* __restrict__ Bt,
                                          const float* __restrict__ bias, const float* __restrict__ scale,
                                          void* __restrict__ Cout, int tm, int tn) {
    __shared__ bf16 sA[128 * 64];   // 16 KB
    __shared__ bf16 sB[256 * 64];   // 32 KB
    int tid = threadIdx.x, w = tid >> 6, lane = tid & 63;
    int wr = w >> 1, wc = w & 1;    // wave tile: rows wr*64..+63, cols wc*128..+127
    int l15 = lane & 15, l4 = lane >> 4;
    int xorb = (l15 & 7) << 4;

    const char* gA = (const char*)A + (size_t)tm * 128 * (HID2 * 2);
    const char* gB = (const char*)Bt + (size_t)tn * 256 * (HID2 * 2);
    const char* pa = (const char*)sA;
    const char* pb = (const char*)sB;

    f32x4 acc[4][8] = {};

    for (int t = 0; t < HID2 / 64; ++t) {
        stage12(gA, gB, (char*)sA, (char*)sB, w, lane, (size_t)t * 128);
        __syncthreads();
#pragma unroll
        for (int kk = 0; kk < 2; ++kk) {
            int kc = (kk * 64 + l4 * 16) ^ xorb;
            bf16x8 af[4], bg[4];
#pragma unroll
            for (int m = 0; m < 4; ++m)
                af[m] = *(const bf16x8*)(pa + (wr * 64 + m * 16 + l15) * 128 + kc);
            // B group 0 (n = 0..3)
#pragma unroll
            for (int n = 0; n < 4; ++n)
                bg[n] = *(const bf16x8*)(pb + (wc * 128 + n * 16 + l15) * 128 + kc);
#pragma unroll
            for (int m = 0; m < 4; ++m)
#pragma unroll
                for (int n = 0; n < 4; ++n)
                    acc[m][n] = __builtin_amdgcn_mfma_f32_16x16x32_bf16(af[m], bg[n], acc[m][n], 0, 0, 0);
            // B group 1 (n = 4..7)
#pragma unroll
            for (int n = 0; n < 4; ++n)
                bg[n] = *(const bf16x8*)(pb + (wc * 128 + (n + 4) * 16 + l15) * 128 + kc);
#pragma unroll
            for (int m = 0; m < 4; ++m)
#pragma unroll
                for (int n = 0; n < 4; ++n)
                    acc[m][n + 4] = __builtin_amdgcn_mfma_f32_16x16x32_bf16(af[m], bg[n], acc[m][n + 4], 0, 0, 0);
        }
        __syncthreads();
    }

    // epilogue
#pragma unroll
    for (int n = 0; n < 8; ++n) {
        int col = tn * 256 + wc * 128 + n * 16 + l15;
        float bv = bias[col];
        float sc = (MODE == 0) ? scale[col] : 0.f;
#pragma unroll
        for (int m = 0; m < 4; ++m) {
            int row = tm * 128 + wr * 64 + m * 16 + l4 * 4;
            if (MODE == 0) {
                bf16* Cp = (bf16*)Cout;
#pragma unroll
                for (int r = 0; r < 4; ++r)
                    Cp[(size_t)(row + r) * HID2 + col] = (bf16)(fabsf(acc[m][n][r] + bv) * sc);
            } else {
                float* Cp = (float*)Cout;
#pragma unroll
                for (int r = 0; r < 4; ++r)
                    Cp[(size_t)(row + r) * HID2 + col] = acc[m][n][r] + bv;
            }
        }
    }
}

__global__ __launch_bounds__(256, 2) void gemm_qkv(
    const bf16* __restrict__ X, const bf16* __restrict__ Wb,
    const float* __restrict__ bq, const float* __restrict__ bk, const float* __restrict__ bv,
    const float* __restrict__ scales, bf16* __restrict__ QKV) {
    int bid = blockIdx.x;           // 0..767 = 3 exact rounds of 256 CUs
    int p = bid & 7, q = bid >> 3;  // XCD p keeps B-panel p resident per z
    int z = q >> 5, tm = q & 31, tn = p;
    const bf16* W = Wb + (size_t)z * HID2 * HID2;
    const float* bias = (z == 0) ? bq : (z == 1) ? bk : bv;
    gemm_core<0>(X, W, bias, scales + z * HID2, QKV + (size_t)z * MROWS * HID2, tm, tn);
}

__global__ __launch_bounds__(256, 2) void gemm_out(
    const bf16* __restrict__ Ctx, const bf16* __restrict__ Wo,
    const float* __restrict__ bo, float* __restrict__ out) {
    int bid = blockIdx.x;           // 0..255 = 1 exact round
    int tn = bid & 7, tm = bid >> 3;
    gemm_core<1>(Ctx, Wo, bo, nullptr, out, tm, tn);
}

// ---------------------------------------------------------------- V transpose
__global__ void transpose_v(const bf16* __restrict__ Vb, bf16* __restrict__ Vt) {
    int bh = blockIdx.z;
    int b = bh >> 4, h = bh & 15;
    int s0 = blockIdx.x * 64, d0 = blockIdx.y * 64;
    int tid = threadIdx.x;
    __shared__ bf16 T[64][72];
    const bf16* src = Vb + ((size_t)b * NS + s0) * HID2 + h * ND + d0;
#pragma unroll
    for (int i = 0; i < 2; ++i) {
        int r = i * 32 + (tid >> 3);
        int c = (tid & 7) * 8;
        *(bf16x8*)(&T[r][c]) = *(const bf16x8*)(src + (size_t)r * HID2 + c);
    }
    __syncthreads();
    bf16* dst = Vt + ((size_t)(b * NH + h) * ND + d0) * NS + s0;
#pragma unroll
    for (int i = 0; i < 2; ++i) {
        int dr = i * 32 + (tid >> 3);
        int sc = (tid & 7) * 8;
        bf16x8 o;
#pragma unroll
        for (int j = 0; j < 8; ++j) o[j] = T[sc + j][dr];
        *(bf16x8*)(dst + (size_t)dr * NS + sc) = o;
    }
}

// ---------------------------------------------------------------- flash attention (v2)
__device__ __forceinline__ void stage_load(const bf16* __restrict__ Kp, const bf16* __restrict__ Vp,
                                           int kt, int tid, bf16x8 kreg[4], bf16x8 vreg[4]) {
#pragma unroll
    for (int i = 0; i < 4; ++i) {
        kreg[i] = *(const bf16x8*)(Kp + (size_t)(kt * 64 + i * 16 + (tid >> 4)) * HID2 + (tid & 15) * 8);
        vreg[i] = *(const bf16x8*)(Vp + (size_t)(i * 32 + (tid >> 3)) * NS + kt * 64 + (tid & 7) * 8);
    }
}

__global__ __launch_bounds__(256, 2) void flash_kernel(
    const bf16* __restrict__ Qb, const bf16* __restrict__ Kb, const bf16* __restrict__ Vt,
    const float* __restrict__ ent, const float* __restrict__ mask, bf16* __restrict__ Ctx) {
    int qt = blockIdx.x;   // 0..15
    int bh = blockIdx.y;   // 0..31
    int b = bh >> 4, h = bh & 15;
    int tid = threadIdx.x, wid = tid >> 6, lane = tid & 63;
    int l15 = lane & 15, l4 = lane >> 4;

    __shared__ bf16 Ks[64 * 136];
    __shared__ bf16 Vs[128 * 72];
    __shared__ bf16 Ps[4][32 * 72];

    const bf16* Qp = Qb + ((size_t)b * NS + qt * 128) * HID2 + h * ND;
    const bf16* Kp = Kb + (size_t)b * NS * HID2 + h * ND;
    const bf16* Vp = Vt + (size_t)(b * NH + h) * ND * NS;
    const float* maskp = mask + (size_t)b * NS;

    bf16x8 qf[2][4];
#pragma unroll
    for (int m = 0; m < 2; ++m)
#pragma unroll
        for (int kk = 0; kk < 4; ++kk)
            qf[m][kk] = *(const bf16x8*)(Qp + (size_t)(wid * 32 + m * 16 + l15) * HID2 + kk * 32 + l4 * 8);

    float eb[4];
#pragma unroll
    for (int r = 0; r < 4; ++r) eb[r] = ent[h * NH + l4 * 4 + r];
    const float RSQD = 0.08838834764831845f;

    float mrun[2], lrun[2];
    mrun[0] = mrun[1] = -INFINITY;
    lrun[0] = lrun[1] = 0.f;
    f32x4 oacc[2][8] = {};

    bf16x8 kreg[4], vreg[4];
    stage_load(Kp, Vp, 0, tid, kreg, vreg);
#pragma unroll
    for (int i = 0; i < 4; ++i) {
        *(bf16x8*)(&Ks[(i * 16 + (tid >> 4)) * 136 + (tid & 15) * 8]) = kreg[i];
        *(bf16x8*)(&Vs[(i * 32 + (tid >> 3)) * 72 + (tid & 7) * 8]) = vreg[i];
    }

    for (int kt = 0; kt < NS / 64; ++kt) {
        __syncthreads();
        if (kt + 1 < NS / 64) stage_load(Kp, Vp, kt + 1, tid, kreg, vreg);

        f32x4 s[2][4] = {};
#pragma unroll
        for (int kk = 0; kk < 4; ++kk) {
            bf16x8 kf[4];
#pragma unroll
            for (int n = 0; n < 4; ++n)
                kf[n] = *(const bf16x8*)(&Ks[(n * 16 + l15) * 136 + kk * 32 + l4 * 8]);
#pragma unroll
            for (int m = 0; m < 2; ++m)
#pragma unroll
                for (int n = 0; n < 4; ++n)
                    s[m][n] = __builtin_amdgcn_mfma_f32_16x16x32_bf16(kf[n], qf[m][kk], s[m][n], 0, 0, 0);
        }

        float4 mk[4];
#pragma unroll
        for (int n = 0; n < 4; ++n)
            mk[n] = *(const float4*)(maskp + kt * 64 + n * 16 + l4 * 4);

#pragma unroll
        for (int mq = 0; mq < 2; ++mq) {
            float sv[4][4];
#pragma unroll
            for (int n = 0; n < 4; ++n) {
                sv[n][0] = s[mq][n][0] * RSQD + eb[0] + mk[n].x;
                sv[n][1] = s[mq][n][1] * RSQD + eb[1] + mk[n].y;
                sv[n][2] = s[mq][n][2] * RSQD + eb[2] + mk[n].z;
                sv[n][3] = s[mq][n][3] * RSQD + eb[3] + mk[n].w;
            }
            float tmax = sv[0][0];
#pragma unroll
            for (int n = 0; n < 4; ++n)
#pragma unroll
                for (int r = 0; r < 4; ++r) tmax = fmaxf(tmax, sv[n][r]);
            tmax = fmaxf(tmax, __shfl_xor(tmax, 16));
            tmax = fmaxf(tmax, __shfl_xor(tmax, 32));

            if (__any(tmax > mrun[mq] + 8.0f)) {
                float mnew = fmaxf(mrun[mq], tmax);
                float corr = __expf(mrun[mq] - mnew);
                mrun[mq] = mnew;
                lrun[mq] *= corr;
#pragma unroll
                for (int r = 0; r < 4; ++r) {
                    float cr = __shfl(corr, l4 * 4 + r);
#pragma unroll
                    for (int n = 0; n < 8; ++n) oacc[mq][n][r] *= cr;
                }
            }

            float psum = 0.f;
#pragma unroll
            for (int n = 0; n < 4; ++n) {
                bf16x4 pv;
#pragma unroll
                for (int r = 0; r < 4; ++r) {
                    float p = __expf(sv[n][r] - mrun[mq]);
                    psum += p;
                    pv[r] = (bf16)p;
                }
                *(bf16x4*)(&Ps[wid][(mq * 16 + l15) * 72 + n * 16 + l4 * 4]) = pv;
            }
            psum += __shfl_xor(psum, 16);
            psum += __shfl_xor(psum, 32);
            lrun[mq] += psum;
        }

#pragma unroll
        for (int kk = 0; kk < 2; ++kk) {
            bf16x8 pa[2], vb[8];
#pragma unroll
            for (int m = 0; m < 2; ++m)
                pa[m] = *(const bf16x8*)(&Ps[wid][(m * 16 + l15) * 72 + kk * 32 + l4 * 8]);
#pragma unroll
            for (int n = 0; n < 8; ++n)
                vb[n] = *(const bf16x8*)(&Vs[(n * 16 + l15) * 72 + kk * 32 + l4 * 8]);
#pragma unroll
            for (int m = 0; m < 2; ++m)
#pragma unroll
                for (int n = 0; n < 8; ++n)
                    oacc[m][n] = __builtin_amdgcn_mfma_f32_16x16x32_bf16(pa[m], vb[n], oacc[m][n], 0, 0, 0);
        }
        __syncthreads();
        if (kt + 1 < NS / 64) {
#pragma unroll
            for (int i = 0; i < 4; ++i) {
                *(bf16x8*)(&Ks[(i * 16 + (tid >> 4)) * 136 + (tid & 15) * 8]) = kreg[i];
                *(bf16x8*)(&Vs[(i * 32 + (tid >> 3)) * 72 + (tid & 7) * 8]) = vreg[i];
            }
        }
    }

#pragma unroll
    for (int m = 0; m < 2; ++m) {
        float inv = 1.0f / lrun[m];
        float invr[4];
#pragma unroll
        for (int r = 0; r < 4; ++r) invr[r] = __shfl(inv, l4 * 4 + r);
#pragma unroll
        for (int r = 0; r < 4; ++r) {
            int row = qt * 128 + wid * 32 + m * 16 + l4 * 4 + r;
            bf16* Cp = Ctx + ((size_t)b * NS + row) * HID2 + h * ND;
#pragma unroll
            for (int n = 0; n < 8; ++n)
                Cp[n * 16 + l15] = (bf16)(oacc[m][n][r] * invr[r]);
        }
    }
}

// ---------------------------------------------------------------- launch
extern "C" void kernel_launch(void* const* d_in, const int* in_sizes, int n_in,
                              void* d_out, int out_size, void* d_ws, size_t ws_size,
                              hipStream_t stream) {
    const float* hidden = (const float*)d_in[0];
    const float* mask   = (const float*)d_in[1];
    const float* q_real = (const float*)d_in[2];
    const float* q_imag = (const float*)d_in[3];
    const float* q_mag  = (const float*)d_in[5];
    const float* k_real = (const float*)d_in[6];
    const float* k_imag = (const float*)d_in[7];
    const float* k_mag  = (const float*)d_in[9];
    const float* v_real = (const float*)d_in[10];
    const float* v_imag = (const float*)d_in[11];
    const float* v_mag  = (const float*)d_in[13];
    const float* Wq = (const float*)d_in[14];
    const float* bq = (const float*)d_in[15];
    const float* Wk = (const float*)d_in[16];
    const float* bk = (const float*)d_in[17];
    const float* Wv = (const float*)d_in[18];
    const float* bv = (const float*)d_in[19];
    const float* Wo = (const float*)d_in[20];
    const float* bo = (const float*)d_in[21];
    const float* ent = (const float*)d_in[22];

    char* ws = (char*)d_ws;
    bf16* Xb    = (bf16*)(ws);
    bf16* Wb    = (bf16*)(ws + 16777216);        // Wq,Wk,Wv,Wo bf16 contiguous
    bf16* Wob   = (bf16*)(ws + 41943040);
    bf16* QKV   = (bf16*)(ws + 50331648);
    bf16* Vt    = (bf16*)(ws + 100663296);
    bf16* Ctx   = (bf16*)(ws + 117440512);
    float* scales = (float*)(ws + 134217728);

    cvt_f32_bf16<<<4096, 256, 0, stream>>>(hidden, Xb, MROWS * HID2 / 8);
    cvt_w4<<<dim3(2048, 4), 256, 0, stream>>>(Wq, Wk, Wv, Wo, Wb);
    qscale_kernel<<<8, 256, 0, stream>>>(q_real, q_imag, q_mag, k_real, k_imag, k_mag,
                                         v_real, v_imag, v_mag, scales);
    gemm_qkv<<<768, 256, 0, stream>>>(Xb, Wb, bq, bk, bv, scales, QKV);
    const bf16* Vb = QKV + (size_t)2 * MROWS * HID2;
    transpose_v<<<dim3(32, 2, 32), 256, 0, stream>>>(Vb, Vt);
    flash_kernel<<<dim3(16, 32), 256, 0, stream>>>(QKV, QKV + (size_t)MROWS * HID2, Vt, ent, mask, Ctx);
    gemm_out<<<256, 256, 0, stream>>>(Ctx, Wob, bo, (float*)d_out);
}

// Round 8
// 290.527 us; speedup vs baseline: 1.1697x; 1.0711x over previous
//
#include <hip/hip_runtime.h>
#include <hip/hip_bf16.h>

#define NB 2
#define NS 2048
#define NH 16
#define ND 128
#define HID2 2048
#define MROWS 4096   // NB*NS

typedef __bf16 bf16;
typedef bf16 bf16x8 __attribute__((ext_vector_type(8)));
typedef bf16 bf16x4 __attribute__((ext_vector_type(4)));
typedef float f32x4 __attribute__((ext_vector_type(4)));
typedef unsigned int u32;

#define GLOBAL_AS __attribute__((address_space(1)))
#define LDS_AS __attribute__((address_space(3)))

__device__ __forceinline__ void async16(void* lds, const void* g) {
    __builtin_amdgcn_global_load_lds((const GLOBAL_AS u32*)g, (LDS_AS u32*)lds, 16, 0, 0);
}

// ---------------------------------------------------------------- converts
__global__ void cvt_f32_bf16(const float* __restrict__ src, bf16* __restrict__ dst, int n8) {
    int i = blockIdx.x * blockDim.x + threadIdx.x;
    if (i >= n8) return;
    const float4* s4 = (const float4*)src;
    float4 a = s4[2 * i], b = s4[2 * i + 1];
    bf16x8 o;
    o[0] = (bf16)a.x; o[1] = (bf16)a.y; o[2] = (bf16)a.z; o[3] = (bf16)a.w;
    o[4] = (bf16)b.x; o[5] = (bf16)b.y; o[6] = (bf16)b.z; o[7] = (bf16)b.w;
    ((bf16x8*)dst)[i] = o;
}

__global__ void cvt_w4(const float* __restrict__ Wq, const float* __restrict__ Wk,
                       const float* __restrict__ Wv, const float* __restrict__ Wo,
                       bf16* __restrict__ dst) {
    int z = blockIdx.y;
    const float* src = (z == 0) ? Wq : (z == 1) ? Wk : (z == 2) ? Wv : Wo;
    int i = blockIdx.x * blockDim.x + threadIdx.x;
    const float4* s4 = (const float4*)src;
    float4 a = s4[2 * i], b = s4[2 * i + 1];
    bf16x8 o;
    o[0] = (bf16)a.x; o[1] = (bf16)a.y; o[2] = (bf16)a.z; o[3] = (bf16)a.w;
    o[4] = (bf16)b.x; o[5] = (bf16)b.y; o[6] = (bf16)b.z; o[7] = (bf16)b.w;
    ((bf16x8*)(dst + (size_t)z * HID2 * HID2))[i] = o;
}

__global__ void qscale_kernel(const float* qr, const float* qi, const float* qm,
                              const float* kr, const float* ki, const float* km,
                              const float* vr, const float* vi, const float* vm,
                              float* out) {
    int i = blockIdx.x * blockDim.x + threadIdx.x;
    if (i >= HID2) return;
    out[i]            = sqrtf(qr[i] * qr[i] + qi[i] * qi[i]) * fabsf(qm[i]);
    out[HID2 + i]     = sqrtf(kr[i] * kr[i] + ki[i] * ki[i]) * fabsf(km[i]);
    out[2 * HID2 + i] = sqrtf(vr[i] * vr[i] + vi[i] * vi[i]) * fabsf(vm[i]);
}

// ---------------------------------------------------------------- phased GEMM (r4 + fixes)
// C[M,N] = A[M,K] @ Bt[N,K]^T. Tile 128x256, BK=64, 8 waves (2M x 4N), 512 thr.
// 3 LDS buffers (48KB ea, 144KB): stage tile t+2 while computing t; staging
// order free (target buffer never concurrently read). Per-wave vmcnt counts
// only own loads -> counted vmcnt(6) at tile end (t+1 landed, t+2 in flight).
// 2 phases/tile (kk=0,1), each: {ds_read 8; stage 2-4; barrier; lgkmcnt(0);
// sched_barrier; setprio1; 16 MFMA; setprio0; barrier}.
// Swizzle byte ^= (r&7)<<4: PROVEN zero-conflict (r5/r7).
__device__ __forceinline__ void stage2A(const char* gA, char* sa, int w, int lane, size_t kb) {
#pragma unroll
    for (int j = 0; j < 2; ++j) {
        int r = w * 16 + j * 8 + (lane >> 3);
        async16(sa + (w * 16 + j * 8) * 128,
                gA + (size_t)r * (HID2 * 2) + kb + (((lane & 7) * 16) ^ ((r & 7) << 4)));
    }
}
__device__ __forceinline__ void stage2B(const char* gB, char* sb, int w, int lane, int half, size_t kb) {
#pragma unroll
    for (int j = 0; j < 2; ++j) {
        int r = half * 128 + w * 16 + j * 8 + (lane >> 3);
        async16(sb + (half * 128 + w * 16 + j * 8) * 128,
                gB + (size_t)r * (HID2 * 2) + kb + (((lane & 7) * 16) ^ ((r & 7) << 4)));
    }
}

#define G_BARRIER() do { asm volatile("" ::: "memory"); __builtin_amdgcn_s_barrier(); \
                         asm volatile("" ::: "memory"); } while (0)

template <int MODE>  // 0: bf16 out = |acc+bias|*scale ; 1: f32 out = acc+bias
__device__ __forceinline__ void gemm_core(const bf16* __restrict__ A, const bf16* __restrict__ Bt,
                                          const float* __restrict__ bias, const float* __restrict__ scale,
                                          void* __restrict__ Cout, int tm, int tn) {
    __shared__ bf16 sA[3][128 * 64];
    __shared__ bf16 sB[3][256 * 64];
    const int NT = HID2 / 64;  // 32
    int tid = threadIdx.x, w = tid >> 6, lane = tid & 63;
    int wr = w >> 2, wc = w & 3;          // wave tile 64x64
    int l15 = lane & 15, l4 = lane >> 4;
    int xorb = (l15 & 7) << 4;

    const char* gA = (const char*)A + (size_t)tm * 128 * (HID2 * 2);
    const char* gB = (const char*)Bt + (size_t)tn * 256 * (HID2 * 2);

    f32x4 acc[4][4] = {};

    // prologue: tiles 0,1 fully staged; wait tile 0 (own 6 of 12 loads)
    stage2A(gA, (char*)sA[0], w, lane, 0);
    stage2B(gB, (char*)sB[0], w, lane, 0, 0);
    stage2B(gB, (char*)sB[0], w, lane, 1, 0);
    stage2A(gA, (char*)sA[1], w, lane, 128);
    stage2B(gB, (char*)sB[1], w, lane, 0, 128);
    stage2B(gB, (char*)sB[1], w, lane, 1, 128);
    asm volatile("s_waitcnt vmcnt(6)" ::: "memory");
    G_BARRIER();

    int cur = 0;
    for (int t = 0; t < NT; ++t) {
        const char* pa = (const char*)sA[cur];
        const char* pb = (const char*)sB[cur];
        int nb = cur + 2; if (nb >= 3) nb -= 3;
        const bool pre = (t + 2 < NT);
        size_t kb = (size_t)(t + 2) * 128;
        bf16x8 af[4], bg[4];

        // ---- phase 0 (kk=0)
        {
            int kc = (l4 * 16) ^ xorb;
#pragma unroll
            for (int m = 0; m < 4; ++m)
                af[m] = *(const bf16x8*)(pa + (wr * 64 + m * 16 + l15) * 128 + kc);
#pragma unroll
            for (int n = 0; n < 4; ++n)
                bg[n] = *(const bf16x8*)(pb + (wc * 64 + n * 16 + l15) * 128 + kc);
        }
        if (pre) { stage2A(gA, (char*)sA[nb], w, lane, kb); stage2B(gB, (char*)sB[nb], w, lane, 0, kb); }
        G_BARRIER();
        asm volatile("s_waitcnt lgkmcnt(0)" ::: "memory");
        __builtin_amdgcn_sched_barrier(0);
        __builtin_amdgcn_s_setprio(1);
#pragma unroll
        for (int m = 0; m < 4; ++m)
#pragma unroll
            for (int n = 0; n < 4; ++n)
                acc[m][n] = __builtin_amdgcn_mfma_f32_16x16x32_bf16(af[m], bg[n], acc[m][n], 0, 0, 0);
        __builtin_amdgcn_s_setprio(0);
        G_BARRIER();

        // ---- phase 1 (kk=1)
        {
            int kc = (64 + l4 * 16) ^ xorb;
#pragma unroll
            for (int m = 0; m < 4; ++m)
                af[m] = *(const bf16x8*)(pa + (wr * 64 + m * 16 + l15) * 128 + kc);
#pragma unroll
            for (int n = 0; n < 4; ++n)
                bg[n] = *(const bf16x8*)(pb + (wc * 64 + n * 16 + l15) * 128 + kc);
        }
        if (pre) stage2B(gB, (char*)sB[nb], w, lane, 1, kb);
        G_BARRIER();
        asm volatile("s_waitcnt lgkmcnt(0)" ::: "memory");
        __builtin_amdgcn_sched_barrier(0);
        __builtin_amdgcn_s_setprio(1);
#pragma unroll
        for (int m = 0; m < 4; ++m)
#pragma unroll
            for (int n = 0; n < 4; ++n)
                acc[m][n] = __builtin_amdgcn_mfma_f32_16x16x32_bf16(af[m], bg[n], acc[m][n], 0, 0, 0);
        __builtin_amdgcn_s_setprio(0);
        // counted wait: tile t+1 (older loads) landed; t+2's 6 stay in flight
        if (pre)                { asm volatile("s_waitcnt vmcnt(6)" ::: "memory"); }
        else if (t + 2 == NT)  { asm volatile("s_waitcnt vmcnt(0)" ::: "memory"); }
        G_BARRIER();

        cur = cur + 1; if (cur == 3) cur = 0;
    }

    // epilogue
#pragma unroll
    for (int n = 0; n < 4; ++n) {
        int col = tn * 256 + wc * 64 + n * 16 + l15;
        float bv = bias[col];
        float sc = (MODE == 0) ? scale[col] : 0.f;
#pragma unroll
        for (int m = 0; m < 4; ++m) {
            int row = tm * 128 + wr * 64 + m * 16 + l4 * 4;
            if (MODE == 0) {
                bf16* Cp = (bf16*)Cout;
#pragma unroll
                for (int r = 0; r < 4; ++r)
                    Cp[(size_t)(row + r) * HID2 + col] = (bf16)(fabsf(acc[m][n][r] + bv) * sc);
            } else {
                float* Cp = (float*)Cout;
#pragma unroll
                for (int r = 0; r < 4; ++r)
                    Cp[(size_t)(row + r) * HID2 + col] = acc[m][n][r] + bv;
            }
        }
    }
}

__global__ __launch_bounds__(512, 2) void gemm_qkv(
    const bf16* __restrict__ X, const bf16* __restrict__ Wb,
    const float* __restrict__ bq, const float* __restrict__ bk, const float* __restrict__ bv,
    const float* __restrict__ scales, bf16* __restrict__ QKV) {
    int z = blockIdx.y;
    int bid = blockIdx.x;             // 0..255 per z; 768 total = 3 exact rounds @1/CU
    int tn = bid & 7, tm = bid >> 3;  // XCD p keeps B-panel p L2-resident
    const bf16* W = Wb + (size_t)z * HID2 * HID2;
    const float* bias = (z == 0) ? bq : (z == 1) ? bk : bv;
    gemm_core<0>(X, W, bias, scales + z * HID2, QKV + (size_t)z * MROWS * HID2, tm, tn);
}

__global__ __launch_bounds__(512, 2) void gemm_out(
    const bf16* __restrict__ Ctx, const bf16* __restrict__ Wo,
    const float* __restrict__ bo, float* __restrict__ out) {
    int bid = blockIdx.x;             // 0..255 = 1 exact round
    int tn = bid & 7, tm = bid >> 3;
    gemm_core<1>(Ctx, Wo, bo, nullptr, out, tm, tn);
}

// ---------------------------------------------------------------- V transpose
__global__ void transpose_v(const bf16* __restrict__ Vb, bf16* __restrict__ Vt) {
    int bh = blockIdx.z;
    int b = bh >> 4, h = bh & 15;
    int s0 = blockIdx.x * 64, d0 = blockIdx.y * 64;
    int tid = threadIdx.x;
    __shared__ bf16 T[64][72];
    const bf16* src = Vb + ((size_t)b * NS + s0) * HID2 + h * ND + d0;
#pragma unroll
    for (int i = 0; i < 2; ++i) {
        int r = i * 32 + (tid >> 3);
        int c = (tid & 7) * 8;
        *(bf16x8*)(&T[r][c]) = *(const bf16x8*)(src + (size_t)r * HID2 + c);
    }
    __syncthreads();
    bf16* dst = Vt + ((size_t)(b * NH + h) * ND + d0) * NS + s0;
#pragma unroll
    for (int i = 0; i < 2; ++i) {
        int dr = i * 32 + (tid >> 3);
        int sc = (tid & 7) * 8;
        bf16x8 o;
#pragma unroll
        for (int j = 0; j < 8; ++j) o[j] = T[sc + j][dr];
        *(bf16x8*)(dst + (size_t)dr * NS + sc) = o;
    }
}

// ---------------------------------------------------------------- flash attention (v2)
__device__ __forceinline__ void stage_load(const bf16* __restrict__ Kp, const bf16* __restrict__ Vp,
                                           int kt, int tid, bf16x8 kreg[4], bf16x8 vreg[4]) {
#pragma unroll
    for (int i = 0; i < 4; ++i) {
        kreg[i] = *(const bf16x8*)(Kp + (size_t)(kt * 64 + i * 16 + (tid >> 4)) * HID2 + (tid & 15) * 8);
        vreg[i] = *(const bf16x8*)(Vp + (size_t)(i * 32 + (tid >> 3)) * NS + kt * 64 + (tid & 7) * 8);
    }
}

__global__ __launch_bounds__(256, 2) void flash_kernel(
    const bf16* __restrict__ Qb, const bf16* __restrict__ Kb, const bf16* __restrict__ Vt,
    const float* __restrict__ ent, const float* __restrict__ mask, bf16* __restrict__ Ctx) {
    int qt = blockIdx.x;   // 0..15
    int bh = blockIdx.y;   // 0..31
    int b = bh >> 4, h = bh & 15;
    int tid = threadIdx.x, wid = tid >> 6, lane = tid & 63;
    int l15 = lane & 15, l4 = lane >> 4;

    __shared__ bf16 Ks[64 * 136];
    __shared__ bf16 Vs[128 * 72];
    __shared__ bf16 Ps[4][32 * 72];

    const bf16* Qp = Qb + ((size_t)b * NS + qt * 128) * HID2 + h * ND;
    const bf16* Kp = Kb + (size_t)b * NS * HID2 + h * ND;
    const bf16* Vp = Vt + (size_t)(b * NH + h) * ND * NS;
    const float* maskp = mask + (size_t)b * NS;

    bf16x8 qf[2][4];
#pragma unroll
    for (int m = 0; m < 2; ++m)
#pragma unroll
        for (int kk = 0; kk < 4; ++kk)
            qf[m][kk] = *(const bf16x8*)(Qp + (size_t)(wid * 32 + m * 16 + l15) * HID2 + kk * 32 + l4 * 8);

    float eb[4];
#pragma unroll
    for (int r = 0; r < 4; ++r) eb[r] = ent[h * NH + l4 * 4 + r];
    const float RSQD = 0.08838834764831845f;

    float mrun[2], lrun[2];
    mrun[0] = mrun[1] = -INFINITY;
    lrun[0] = lrun[1] = 0.f;
    f32x4 oacc[2][8] = {};

    bf16x8 kreg[4], vreg[4];
    stage_load(Kp, Vp, 0, tid, kreg, vreg);
#pragma unroll
    for (int i = 0; i < 4; ++i) {
        *(bf16x8*)(&Ks[(i * 16 + (tid >> 4)) * 136 + (tid & 15) * 8]) = kreg[i];
        *(bf16x8*)(&Vs[(i * 32 + (tid >> 3)) * 72 + (tid & 7) * 8]) = vreg[i];
    }

    for (int kt = 0; kt < NS / 64; ++kt) {
        __syncthreads();
        if (kt + 1 < NS / 64) stage_load(Kp, Vp, kt + 1, tid, kreg, vreg);

        f32x4 s[2][4] = {};
#pragma unroll
        for (int kk = 0; kk < 4; ++kk) {
            bf16x8 kf[4];
#pragma unroll
            for (int n = 0; n < 4; ++n)
                kf[n] = *(const bf16x8*)(&Ks[(n * 16 + l15) * 136 + kk * 32 + l4 * 8]);
#pragma unroll
            for (int m = 0; m < 2; ++m)
#pragma unroll
                for (int n = 0; n < 4; ++n)
                    s[m][n] = __builtin_amdgcn_mfma_f32_16x16x32_bf16(kf[n], qf[m][kk], s[m][n], 0, 0, 0);
        }

        float4 mk[4];
#pragma unroll
        for (int n = 0; n < 4; ++n)
            mk[n] = *(const float4*)(maskp + kt * 64 + n * 16 + l4 * 4);

#pragma unroll
        for (int mq = 0; mq < 2; ++mq) {
            float sv[4][4];
#pragma unroll
            for (int n = 0; n < 4; ++n) {
                sv[n][0] = s[mq][n][0] * RSQD + eb[0] + mk[n].x;
                sv[n][1] = s[mq][n][1] * RSQD + eb[1] + mk[n].y;
                sv[n][2] = s[mq][n][2] * RSQD + eb[2] + mk[n].z;
                sv[n][3] = s[mq][n][3] * RSQD + eb[3] + mk[n].w;
            }
            float tmax = sv[0][0];
#pragma unroll
            for (int n = 0; n < 4; ++n)
#pragma unroll
                for (int r = 0; r < 4; ++r) tmax = fmaxf(tmax, sv[n][r]);
            tmax = fmaxf(tmax, __shfl_xor(tmax, 16));
            tmax = fmaxf(tmax, __shfl_xor(tmax, 32));

            if (__any(tmax > mrun[mq] + 8.0f)) {
                float mnew = fmaxf(mrun[mq], tmax);
                float corr = __expf(mrun[mq] - mnew);
                mrun[mq] = mnew;
                lrun[mq] *= corr;
#pragma unroll
                for (int r = 0; r < 4; ++r) {
                    float cr = __shfl(corr, l4 * 4 + r);
#pragma unroll
                    for (int n = 0; n < 8; ++n) oacc[mq][n][r] *= cr;
                }
            }

            float psum = 0.f;
#pragma unroll
            for (int n = 0; n < 4; ++n) {
                bf16x4 pv;
#pragma unroll
                for (int r = 0; r < 4; ++r) {
                    float p = __expf(sv[n][r] - mrun[mq]);
                    psum += p;
                    pv[r] = (bf16)p;
                }
                *(bf16x4*)(&Ps[wid][(mq * 16 + l15) * 72 + n * 16 + l4 * 4]) = pv;
            }
            psum += __shfl_xor(psum, 16);
            psum += __shfl_xor(psum, 32);
            lrun[mq] += psum;
        }

#pragma unroll
        for (int kk = 0; kk < 2; ++kk) {
            bf16x8 pa[2], vb[8];
#pragma unroll
            for (int m = 0; m < 2; ++m)
                pa[m] = *(const bf16x8*)(&Ps[wid][(m * 16 + l15) * 72 + kk * 32 + l4 * 8]);
#pragma unroll
            for (int n = 0; n < 8; ++n)
                vb[n] = *(const bf16x8*)(&Vs[(n * 16 + l15) * 72 + kk * 32 + l4 * 8]);
#pragma unroll
            for (int m = 0; m < 2; ++m)
#pragma unroll
                for (int n = 0; n < 8; ++n)
                    oacc[m][n] = __builtin_amdgcn_mfma_f32_16x16x32_bf16(pa[m], vb[n], oacc[m][n], 0, 0, 0);
        }
        __syncthreads();
        if (kt + 1 < NS / 64) {
#pragma unroll
            for (int i = 0; i < 4; ++i) {
                *(bf16x8*)(&Ks[(i * 16 + (tid >> 4)) * 136 + (tid & 15) * 8]) = kreg[i];
                *(bf16x8*)(&Vs[(i * 32 + (tid >> 3)) * 72 + (tid & 7) * 8]) = vreg[i];
            }
        }
    }

#pragma unroll
    for (int m = 0; m < 2; ++m) {
        float inv = 1.0f / lrun[m];
        float invr[4];
#pragma unroll
        for (int r = 0; r < 4; ++r) invr[r] = __shfl(inv, l4 * 4 + r);
#pragma unroll
        for (int r = 0; r < 4; ++r) {
            int row = qt * 128 + wid * 32 + m * 16 + l4 * 4 + r;
            bf16* Cp = Ctx + ((size_t)b * NS + row) * HID2 + h * ND;
#pragma unroll
            for (int n = 0; n < 8; ++n)
                Cp[n * 16 + l15] = (bf16)(oacc[m][n][r] * invr[r]);
        }
    }
}

// ---------------------------------------------------------------- launch
extern "C" void kernel_launch(void* const* d_in, const int* in_sizes, int n_in,
                              void* d_out, int out_size, void* d_ws, size_t ws_size,
                              hipStream_t stream) {
    const float* hidden = (const float*)d_in[0];
    const float* mask   = (const float*)d_in[1];
    const float* q_real = (const float*)d_in[2];
    const float* q_imag = (const float*)d_in[3];
    const float* q_mag  = (const float*)d_in[5];
    const float* k_real = (const float*)d_in[6];
    const float* k_imag = (const float*)d_in[7];
    const float* k_mag  = (const float*)d_in[9];
    const float* v_real = (const float*)d_in[10];
    const float* v_imag = (const float*)d_in[11];
    const float* v_mag  = (const float*)d_in[13];
    const float* Wq = (const float*)d_in[14];
    const float* bq = (const float*)d_in[15];
    const float* Wk = (const float*)d_in[16];
    const float* bk = (const float*)d_in[17];
    const float* Wv = (const float*)d_in[18];
    const float* bv = (const float*)d_in[19];
    const float* Wo = (const float*)d_in[20];
    const float* bo = (const float*)d_in[21];
    const float* ent = (const float*)d_in[22];

    char* ws = (char*)d_ws;
    bf16* Xb    = (bf16*)(ws);
    bf16* Wb    = (bf16*)(ws + 16777216);        // Wq,Wk,Wv,Wo bf16 contiguous
    bf16* Wob   = (bf16*)(ws + 41943040);
    bf16* QKV   = (bf16*)(ws + 50331648);
    bf16* Vt    = (bf16*)(ws + 100663296);
    bf16* Ctx   = (bf16*)(ws + 117440512);
    float* scales = (float*)(ws + 134217728);

    cvt_f32_bf16<<<4096, 256, 0, stream>>>(hidden, Xb, MROWS * HID2 / 8);
    cvt_w4<<<dim3(2048, 4), 256, 0, stream>>>(Wq, Wk, Wv, Wo, Wb);
    qscale_kernel<<<8, 256, 0, stream>>>(q_real, q_imag, q_mag, k_real, k_imag, k_mag,
                                         v_real, v_imag, v_mag, scales);
    gemm_qkv<<<dim3(256, 3), 512, 0, stream>>>(Xb, Wb, bq, bk, bv, scales, QKV);
    const bf16* Vb = QKV + (size_t)2 * MROWS * HID2;
    transpose_v<<<dim3(32, 2, 32), 256, 0, stream>>>(Vb, Vt);
    flash_kernel<<<dim3(16, 32), 256, 0, stream>>>(QKV, QKV + (size_t)MROWS * HID2, Vt, ent, mask, Ctx);
    gemm_out<<<256, 512, 0, stream>>>(Ctx, Wob, bo, (float*)d_out);
}